// Round 5
// baseline (274.158 us; speedup 1.0000x reference)
//
#include <hip/hip_runtime.h>

// ---------------------------------------------------------------------------
// Round 19: delete the CSR build machinery. r18 showed the barriers/scan were
// not the cost (-5 us); the expense is k_bin's slot atomics + scattered ptmp
// writes + 3 passes over edge data. Replacement: fixed-stride direct scatter.
//   slot = dst*64 + atomicAdd(dcur[dst],1)   (Poisson(16): P(deg>63)~1e-15)
// One edge-parallel kernel (k_scatter) reads esrc/edst coalesced, computes
// the radial embedding inline (pos L2-resident), writes ebuf records to final
// per-node-contiguous slots. k_bin/k_build/ptmp/offs2 all deleted. Layers
// derive ranges from dcur: [nd*64, nd*64+deg). Layer math untouched.
// Prediction: 233 -> ~140-165 us (build ~130 -> ~15-20). If >=200, residual
// is layers/dispatch overhead -> pivot next round.
// ---------------------------------------------------------------------------

#define DCAP 64        // per-node slot capacity (mean deg 16, +12 sigma)

__device__ __forceinline__ float sus_f(float x) {
    return x > 0.0f ? __expf(-1.0f / x) : 0.0f;
}

__device__ __forceinline__ float uload(const float* p) {
    return __uint_as_float(__builtin_amdgcn_readfirstlane(__float_as_uint(*p)));
}

// --- single build pass: direct scatter + inline emb; block 0 also computes
// G[k][u][c] = sum_w fc3_w2[k][u*16+w] * conv_w[c][w] ------------------------
__global__ __launch_bounds__(256) void k_scatter(
    const int* __restrict__ src, const int* __restrict__ dst,
    const float* __restrict__ pos,
    int* __restrict__ dcur, float4* __restrict__ ebuf,
    const float* __restrict__ fc3w2, const float* __restrict__ cw,
    float* __restrict__ gbuf,
    int nedges)
{
    const float C = 1.14136f * 7.3890560989306495f; // 1.14136 * e^2
    int base = blockIdx.x * 2048 + threadIdx.x * 8;
    int ss[8], dd[8];
    if (base + 7 < nedges) {
        int4 s0 = *(const int4*)&src[base];
        int4 s1 = *(const int4*)&src[base + 4];
        int4 d0 = *(const int4*)&dst[base];
        int4 d1 = *(const int4*)&dst[base + 4];
        ss[0]=s0.x; ss[1]=s0.y; ss[2]=s0.z; ss[3]=s0.w;
        ss[4]=s1.x; ss[5]=s1.y; ss[6]=s1.z; ss[7]=s1.w;
        dd[0]=d0.x; dd[1]=d0.y; dd[2]=d0.z; dd[3]=d0.w;
        dd[4]=d1.x; dd[5]=d1.y; dd[6]=d1.z; dd[7]=d1.w;
    } else {
        #pragma unroll
        for (int i = 0; i < 8; ++i) {
            int e = base + i;
            if (e < nedges) { ss[i] = src[e]; dd[i] = dst[e]; }
            else dd[i] = -1;
        }
    }

    #pragma unroll
    for (int i = 0; i < 8; ++i) {
        if (dd[i] < 0) continue;
        int t = dd[i], s = ss[i];
        int r = atomicAdd(&dcur[t], 1);
        float dx = pos[3 * t + 0] - pos[3 * s + 0];
        float dy = pos[3 * t + 1] - pos[3 * s + 1];
        float dz = pos[3 * t + 2] - pos[3 * s + 2];
        float d = sqrtf(dx * dx + dy * dy + dz * dz);
        float e0, e1, e2;
        { float f = (d - 0.75f) * (1.0f / 0.75f);
          e0 = C * sus_f(f + 1.0f) * sus_f(1.0f - f); }
        { float f = (d - 1.50f) * (1.0f / 0.75f);
          e1 = C * sus_f(f + 1.0f) * sus_f(1.0f - f); }
        { float f = (d - 2.25f) * (1.0f / 0.75f);
          e2 = C * sus_f(f + 1.0f) * sus_f(1.0f - f); }
        if (r < DCAP)   // statistically impossible overflow guard
            ebuf[((size_t)t << 6) + r] = make_float4(__int_as_float(s), e0, e1, e2);
    }

    // tiny G-precompute (one block, independent of scatter data)
    if (blockIdx.x == 0 && threadIdx.x < 128) {
        int idx = threadIdx.x;          // k*8 + u*2 + c
        int k = idx >> 3, u = (idx >> 1) & 3, c = idx & 1;
        float s = 0.0f;
        #pragma unroll
        for (int w = 0; w < 16; ++w)
            s = fmaf(fc3w2[k * 64 + u * 16 + w], cw[c * 16 + w], s);
        gbuf[idx] = s;
    }
}

// --- layers: edge-split quads, partial outer product, LDS-W2 epilogue --------
// (identical math to the r15 champion; ranges now [nd*64, nd*64+deg))

__global__ __launch_bounds__(256) void k_node_l1(
    const float* __restrict__ feat, const float4* __restrict__ edata,
    const int* __restrict__ dcur,
    const float* __restrict__ w1, const float* __restrict__ w2,
    float* __restrict__ xout, int n)
{
    __shared__ float lw[16 * 20];
    if (threadIdx.x < 192) {
        int k = threadIdx.x / 12, r = threadIdx.x % 12;
        lw[k * 20 + r] = w2[k * 12 + r];
    }
    __syncthreads();

    int g = blockIdx.x * 256 + threadIdx.x;
    int nd = g >> 2;
    if (nd >= n) return;
    int t = g & 3;

    float w1r[3][16];   // wave-uniform -> SGPRs
    #pragma unroll
    for (int j = 0; j < 3; ++j)
        #pragma unroll
        for (int k = 0; k < 16; ++k) w1r[j][k] = uload(&w1[j * 16 + k]);

    float O[16][3];
    #pragma unroll
    for (int k = 0; k < 16; ++k)
        #pragma unroll
        for (int u = 0; u < 3; ++u) O[k][u] = 0.0f;

    int deg = dcur[nd]; if (deg > DCAP) deg = DCAP;
    int bse = nd << 6;
    for (int e = bse + t; e < bse + deg; e += 4) {
        float4 ed = edata[e];
        int s = __float_as_int(ed.x);
        float f0 = feat[3 * s + 0], f1 = feat[3 * s + 1], f2 = feat[3 * s + 2];
        #pragma unroll
        for (int k = 0; k < 16; ++k) {
            float a = fmaf(ed.y, w1r[0][k], fmaf(ed.z, w1r[1][k], ed.w * w1r[2][k]));
            float h = a > 0.0f ? a : 0.0f;
            O[k][0] = fmaf(h, f0, O[k][0]);
            O[k][1] = fmaf(h, f1, O[k][1]);
            O[k][2] = fmaf(h, f2, O[k][2]);
        }
    }

    float p0 = 0.f, p1 = 0.f, p2 = 0.f, p3 = 0.f;
    #pragma unroll
    for (int k = 0; k < 16; ++k)
        #pragma unroll
        for (int u = 0; u < 3; ++u) {
            const float4 q = *(const float4*)&lw[k * 20 + u * 4];
            float o = O[k][u];
            p0 = fmaf(o, q.x, p0); p1 = fmaf(o, q.y, p1);
            p2 = fmaf(o, q.z, p2); p3 = fmaf(o, q.w, p3);
        }
    p0 += __shfl_xor(p0, 1); p1 += __shfl_xor(p1, 1);
    p2 += __shfl_xor(p2, 1); p3 += __shfl_xor(p3, 1);
    p0 += __shfl_xor(p0, 2); p1 += __shfl_xor(p1, 2);
    p2 += __shfl_xor(p2, 2); p3 += __shfl_xor(p3, 2);
    if (t == 0) {
        const float S = 0.051031036307982884f; // sqrt2/sqrt3/16
        float4 o; o.x = p0 * S; o.y = p1 * S; o.z = p2 * S; o.w = p3 * S;
        ((float4*)xout)[nd] = o;
    }
}

__global__ __launch_bounds__(256) void k_node_core(
    const float4* __restrict__ xin, const float4* __restrict__ edata,
    const int* __restrict__ dcur,
    const float* __restrict__ w1, const float* __restrict__ w2,
    float* __restrict__ xout, int n)
{
    __shared__ float lw[16 * 20];
    {
        int idx = threadIdx.x;
        int k = idx >> 4, r = idx & 15;
        lw[k * 20 + r] = w2[k * 48 + r];
    }
    __syncthreads();

    int g = blockIdx.x * 256 + threadIdx.x;
    int nd = g >> 2;
    if (nd >= n) return;
    int t = g & 3;

    float w1r[3][16];   // wave-uniform -> SGPRs
    #pragma unroll
    for (int j = 0; j < 3; ++j)
        #pragma unroll
        for (int k = 0; k < 16; ++k) w1r[j][k] = uload(&w1[j * 16 + k]);

    float O[16][4];
    #pragma unroll
    for (int k = 0; k < 16; ++k)
        #pragma unroll
        for (int u = 0; u < 4; ++u) O[k][u] = 0.0f;

    int deg = dcur[nd]; if (deg > DCAP) deg = DCAP;
    int bse = nd << 6;
    for (int e = bse + t; e < bse + deg; e += 4) {
        float4 ed = edata[e];
        int s = __float_as_int(ed.x);
        float4 x = xin[s];
        #pragma unroll
        for (int k = 0; k < 16; ++k) {
            float a = fmaf(ed.y, w1r[0][k], fmaf(ed.z, w1r[1][k], ed.w * w1r[2][k]));
            float h = a > 0.0f ? a : 0.0f;
            O[k][0] = fmaf(h, x.x, O[k][0]);
            O[k][1] = fmaf(h, x.y, O[k][1]);
            O[k][2] = fmaf(h, x.z, O[k][2]);
            O[k][3] = fmaf(h, x.w, O[k][3]);
        }
    }

    float p0 = 0.f, p1 = 0.f, p2 = 0.f, p3 = 0.f;
    #pragma unroll
    for (int k = 0; k < 16; ++k)
        #pragma unroll
        for (int u = 0; u < 4; ++u) {
            const float4 q = *(const float4*)&lw[k * 20 + u * 4];
            float o = O[k][u];
            p0 = fmaf(o, q.x, p0); p1 = fmaf(o, q.y, p1);
            p2 = fmaf(o, q.z, p2); p3 = fmaf(o, q.w, p3);
        }
    p0 += __shfl_xor(p0, 1); p1 += __shfl_xor(p1, 1);
    p2 += __shfl_xor(p2, 1); p3 += __shfl_xor(p3, 1);
    p0 += __shfl_xor(p0, 2); p1 += __shfl_xor(p1, 2);
    p2 += __shfl_xor(p2, 2); p3 += __shfl_xor(p3, 2);
    if (t == 0) {
        const float S = 0.04419417382415922f; // sqrt2*0.5/16
        float4 o; o.x = p0 * S; o.y = p1 * S; o.z = p2 * S; o.w = p3 * S;
        ((float4*)xout)[nd] = o;
    }
}

// fc3 + folded 1x1 conv via precomputed G[16][4][2].
__global__ __launch_bounds__(256) void k_node_fc3_final(
    const float4* __restrict__ xin, const float4* __restrict__ edata,
    const int* __restrict__ dcur,
    const float* __restrict__ w1, const float* __restrict__ gbuf,
    const float* __restrict__ cb,
    float* __restrict__ out, int n)
{
    __shared__ float lg[128];
    if (threadIdx.x < 128) lg[threadIdx.x] = gbuf[threadIdx.x];
    __syncthreads();

    int g = blockIdx.x * 256 + threadIdx.x;
    int nd = g >> 2;
    if (nd >= n) return;
    int t = g & 3;

    float w1r[3][16];   // wave-uniform -> SGPRs
    #pragma unroll
    for (int j = 0; j < 3; ++j)
        #pragma unroll
        for (int k = 0; k < 16; ++k) w1r[j][k] = uload(&w1[j * 16 + k]);

    float O[16][4];
    #pragma unroll
    for (int k = 0; k < 16; ++k)
        #pragma unroll
        for (int u = 0; u < 4; ++u) O[k][u] = 0.0f;

    int deg = dcur[nd]; if (deg > DCAP) deg = DCAP;
    int bse = nd << 6;
    for (int e = bse + t; e < bse + deg; e += 4) {
        float4 ed = edata[e];
        int s = __float_as_int(ed.x);
        float4 x = xin[s];
        #pragma unroll
        for (int k = 0; k < 16; ++k) {
            float a = fmaf(ed.y, w1r[0][k], fmaf(ed.z, w1r[1][k], ed.w * w1r[2][k]));
            float h = a > 0.0f ? a : 0.0f;
            O[k][0] = fmaf(h, x.x, O[k][0]);
            O[k][1] = fmaf(h, x.y, O[k][1]);
            O[k][2] = fmaf(h, x.z, O[k][2]);
            O[k][3] = fmaf(h, x.w, O[k][3]);
        }
    }

    float a0 = 0.f, a1 = 0.f;
    #pragma unroll
    for (int k = 0; k < 16; ++k)
        #pragma unroll
        for (int u = 0; u < 4; ++u) {
            float o = O[k][u];
            const float2 q = *(const float2*)&lg[(k * 4 + u) * 2];
            a0 = fmaf(o, q.x, a0);
            a1 = fmaf(o, q.y, a1);
        }
    a0 += __shfl_xor(a0, 1); a1 += __shfl_xor(a1, 1);
    a0 += __shfl_xor(a0, 2); a1 += __shfl_xor(a1, 2);
    if (t == 0) {
        const float S = 0.04419417382415922f;
        float2 o; o.x = fmaf(a0, S, cb[0]); o.y = fmaf(a1, S, cb[1]);
        ((float2*)out)[nd] = o;
    }
}

// ---------------------------------------------------------------------------

extern "C" void kernel_launch(void* const* d_in, const int* in_sizes, int n_in,
                              void* d_out, int out_size, void* d_ws, size_t ws_size,
                              hipStream_t stream) {
    const float* pos     = (const float*)d_in[0];
    const float* feat    = (const float*)d_in[1];
    const int*   esrc    = (const int*)d_in[2];
    const int*   edst    = (const int*)d_in[3];
    const float* fc1_w1  = (const float*)d_in[4];
    const float* fc1_w2  = (const float*)d_in[5];
    const float* core_w1 = (const float*)d_in[6];
    const float* core_w2 = (const float*)d_in[7];
    const float* fc3_w1  = (const float*)d_in[8];
    const float* fc3_w2  = (const float*)d_in[9];
    const float* conv_w  = (const float*)d_in[10];
    const float* conv_b  = (const float*)d_in[11];
    float* out = (float*)d_out;

    const int E = in_sizes[2];          // 1600000
    const int N = in_sizes[0] / 3;      // 100000

    float4* ebuf = (float4*)d_ws;                        // N*64 float4 = 102.4MB
    float* xa  = (float*)(ebuf + ((size_t)N << 6));      // 4N
    float* xb  = xa + (size_t)4 * N;                     // 4N
    int* dcur  = (int*)(xb + (size_t)4 * N);             // N
    float* gbuf = (float*)(dcur + ((N + 3) & ~3));       // 128

    int g4 = (4 * N + 255) / 256;

    hipMemsetAsync(dcur, 0, (size_t)N * sizeof(int), stream);
    k_scatter<<<(E + 2047) / 2048, 256, 0, stream>>>(esrc, edst, pos, dcur, ebuf,
                                                     fc3_w2, conv_w, gbuf, E);

    k_node_l1<<<g4, 256, 0, stream>>>(feat, ebuf, dcur, fc1_w1, fc1_w2, xa, N);
    k_node_core<<<g4, 256, 0, stream>>>((const float4*)xa, ebuf, dcur,
                                        core_w1 + 0, core_w2 + 0, xb, N);
    k_node_core<<<g4, 256, 0, stream>>>((const float4*)xb, ebuf, dcur,
                                        core_w1 + 48, core_w2 + 768, xa, N);
    k_node_core<<<g4, 256, 0, stream>>>((const float4*)xa, ebuf, dcur,
                                        core_w1 + 96, core_w2 + 1536, xb, N);
    k_node_fc3_final<<<g4, 256, 0, stream>>>((const float4*)xb, ebuf, dcur,
                                             fc3_w1, gbuf, conv_b, out, N);
}

// Round 6
// 215.899 us; speedup vs baseline: 1.2698x; 1.2698x over previous
//
#include <hip/hip_runtime.h>

// ---------------------------------------------------------------------------
// Round 20: revert to r18 structure (233 us champion); single change: k_bin
// upgraded to 1024-thread blocks (8192 edges/block).
//   r19 counters proved per-edge random scatter = 110 us (latency-bound:
//   random global atomics + 16B stores each touching a full 64B line, 4x
//   write amplification) AND it poisoned layer read locality (total 274).
//   k_bin's LDS aggregation is the right design; its weakness is run length:
//   2048 edges/391 buckets ~= 5 edges (21 B) per (block,bucket) scattered
//   store. 8192 edges/block -> ~21-edge (84 B ~= cache line) runs, 4x fewer
//   global reservation atomics (306K -> 77K).
// Prediction: k_bin ~70 -> ~30 us => total ~195-210 us. If >=225, k_build
// holds the residual -> duplicate it next round for attribution.
// ---------------------------------------------------------------------------

#define BCAP 4608      // bucket capacity: mean 4096 + 8 sigma
#define NBMAX 400

__device__ __forceinline__ float sus_f(float x) {
    return x > 0.0f ? __expf(-1.0f / x) : 0.0f;
}

__device__ __forceinline__ float uload(const float* p) {
    return __uint_as_float(__builtin_amdgcn_readfirstlane(__float_as_uint(*p)));
}

// --- pass 1: coarse binning, 4 B packed {src<<8 | dst&255}; 1024 threads,
// 8192 edges/block; block 0 also computes G[k][u][c] ------------------------
__global__ __launch_bounds__(1024) void k_bin(
    const int* __restrict__ src, const int* __restrict__ dst,
    int* __restrict__ gcur, int* __restrict__ ptmp,
    const float* __restrict__ fc3w2, const float* __restrict__ cw,
    float* __restrict__ gbuf,
    int nedges, int nb)
{
    __shared__ int cnt[NBMAX];
    __shared__ int gb[NBMAX];
    if (threadIdx.x < NBMAX) cnt[threadIdx.x] = 0;
    __syncthreads();

    int base = blockIdx.x * 8192 + threadIdx.x * 8;
    int pk[8]; int bk[8]; short r[8];
    int ss[8], dd[8];
    if (base + 7 < nedges) {
        int4 s0 = *(const int4*)&src[base];
        int4 s1 = *(const int4*)&src[base + 4];
        int4 d0 = *(const int4*)&dst[base];
        int4 d1 = *(const int4*)&dst[base + 4];
        ss[0]=s0.x; ss[1]=s0.y; ss[2]=s0.z; ss[3]=s0.w;
        ss[4]=s1.x; ss[5]=s1.y; ss[6]=s1.z; ss[7]=s1.w;
        dd[0]=d0.x; dd[1]=d0.y; dd[2]=d0.z; dd[3]=d0.w;
        dd[4]=d1.x; dd[5]=d1.y; dd[6]=d1.z; dd[7]=d1.w;
        #pragma unroll
        for (int i = 0; i < 8; ++i) {
            int b = dd[i] >> 8;
            bk[i] = b;
            pk[i] = (ss[i] << 8) | (dd[i] & 255);
            r[i] = (short)atomicAdd(&cnt[b], 1);
        }
    } else {
        #pragma unroll
        for (int i = 0; i < 8; ++i) {
            int e = base + i;
            if (e < nedges) {
                int s = src[e], t = dst[e];
                int b = t >> 8;
                bk[i] = b;
                pk[i] = (s << 8) | (t & 255);
                r[i] = (short)atomicAdd(&cnt[b], 1);
            } else bk[i] = -1;
        }
    }
    __syncthreads();
    if (threadIdx.x < NBMAX && threadIdx.x < nb) {
        int c = cnt[threadIdx.x];
        gb[threadIdx.x] = c > 0 ? atomicAdd(&gcur[threadIdx.x], c) : 0;
    }
    __syncthreads();
    #pragma unroll
    for (int i = 0; i < 8; ++i) {
        if (bk[i] >= 0) {
            int p = gb[bk[i]] + (int)r[i];
            if (p < BCAP)   // statistically impossible overflow guard
                ptmp[bk[i] * BCAP + p] = pk[i];
        }
    }

    // fold in the tiny G-precompute (one block, independent of binning data)
    if (blockIdx.x == 0 && threadIdx.x < 128) {
        int idx = threadIdx.x;          // k*8 + u*2 + c
        int k = idx >> 3, u = (idx >> 1) & 3, c = idx & 1;
        float s = 0.0f;
        #pragma unroll
        for (int w = 0; w < 16; ++w)
            s = fmaf(fc3w2[k * 64 + u * 16 + w], cw[c * 16 + w], s);
        gbuf[idx] = s;
    }
}

// --- pass 2: per-bucket histogram / wave-scan / permute / emb, 1024 thr -----
__global__ __launch_bounds__(1024) void k_build(
    const int* __restrict__ gcur, const int* __restrict__ ptmp,
    const float* __restrict__ pos,
    float4* __restrict__ ebuf, int2* __restrict__ offs2,
    int n, int nb)
{
    int b = blockIdx.x;
    int cnt = gcur[b]; if (cnt > BCAP) cnt = BCAP;
    int t = threadIdx.x;

    __shared__ int stage[BCAP];
    __shared__ int perm[BCAP];
    __shared__ int deg[256];
    __shared__ int loffs[256];
    __shared__ int cur[256];

    const int* tin = ptmp + b * BCAP;
    for (int j = t; j < cnt; j += 1024) stage[j] = tin[j];
    if (t < 256) deg[t] = 0;
    __syncthreads();

    for (int j = t; j < cnt; j += 1024)
        atomicAdd(&deg[stage[j] & 255], 1);
    __syncthreads();

    // exclusive scan of deg[256] entirely in wave 0: each lane owns 4 bins,
    // 6 shfl_up steps across the wave, zero barriers.
    if (t < 64) {
        int d0 = deg[4 * t + 0], d1 = deg[4 * t + 1];
        int d2 = deg[4 * t + 2], d3 = deg[4 * t + 3];
        int s = d0 + d1 + d2 + d3;
        int x = s;
        #pragma unroll
        for (int off = 1; off < 64; off <<= 1) {
            int y = __shfl_up(x, off);
            if (t >= off) x += y;
        }
        int ex = x - s;   // exclusive prefix of 4-bin group sums
        int e0 = ex, e1 = ex + d0, e2 = e1 + d1, e3 = e2 + d2;
        loffs[4 * t + 0] = e0; cur[4 * t + 0] = e0;
        loffs[4 * t + 1] = e1; cur[4 * t + 1] = e1;
        loffs[4 * t + 2] = e2; cur[4 * t + 2] = e2;
        loffs[4 * t + 3] = e3; cur[4 * t + 3] = e3;
    }
    __syncthreads();

    int nid0 = b << 8;
    {
        int nn = n - nid0; if (nn > 256) nn = 256;
        if (t < nn) {
            int st = b * BCAP + loffs[t];
            offs2[nid0 + t] = make_int2(st, st + deg[t]);
        }
    }

    for (int j = t; j < cnt; j += 1024) {
        int pkd = stage[j];
        perm[atomicAdd(&cur[pkd & 255], 1)] = pkd;
    }
    __syncthreads();

    // radial embedding straight out of LDS perm (no pidx roundtrip)
    const float C = 1.14136f * 7.3890560989306495f; // 1.14136 * e^2
    for (int j = t; j < cnt; j += 1024) {
        int pkd = perm[j];
        int s = pkd >> 8;
        int tt = nid0 | (pkd & 255);
        float dx = pos[3 * tt + 0] - pos[3 * s + 0];
        float dy = pos[3 * tt + 1] - pos[3 * s + 1];
        float dz = pos[3 * tt + 2] - pos[3 * s + 2];
        float d = sqrtf(dx * dx + dy * dy + dz * dz);
        float e0, e1, e2;
        { float f = (d - 0.75f) * (1.0f / 0.75f);
          e0 = C * sus_f(f + 1.0f) * sus_f(1.0f - f); }
        { float f = (d - 1.50f) * (1.0f / 0.75f);
          e1 = C * sus_f(f + 1.0f) * sus_f(1.0f - f); }
        { float f = (d - 2.25f) * (1.0f / 0.75f);
          e2 = C * sus_f(f + 1.0f) * sus_f(1.0f - f); }
        ebuf[(size_t)b * BCAP + j] = make_float4(__int_as_float(s), e0, e1, e2);
    }
}

// --- layers: edge-split quads, partial outer product, LDS-W2 epilogue --------
// (byte-identical to the r15 champion)

__global__ __launch_bounds__(256) void k_node_l1(
    const float* __restrict__ feat, const float4* __restrict__ edata,
    const int2* __restrict__ offs2,
    const float* __restrict__ w1, const float* __restrict__ w2,
    float* __restrict__ xout, int n)
{
    __shared__ float lw[16 * 20];
    if (threadIdx.x < 192) {
        int k = threadIdx.x / 12, r = threadIdx.x % 12;
        lw[k * 20 + r] = w2[k * 12 + r];
    }
    __syncthreads();

    int g = blockIdx.x * 256 + threadIdx.x;
    int nd = g >> 2;
    if (nd >= n) return;
    int t = g & 3;

    float w1r[3][16];   // wave-uniform -> SGPRs
    #pragma unroll
    for (int j = 0; j < 3; ++j)
        #pragma unroll
        for (int k = 0; k < 16; ++k) w1r[j][k] = uload(&w1[j * 16 + k]);

    float O[16][3];
    #pragma unroll
    for (int k = 0; k < 16; ++k)
        #pragma unroll
        for (int u = 0; u < 3; ++u) O[k][u] = 0.0f;

    int2 se = offs2[nd];
    for (int e = se.x + t; e < se.y; e += 4) {
        float4 ed = edata[e];
        int s = __float_as_int(ed.x);
        float f0 = feat[3 * s + 0], f1 = feat[3 * s + 1], f2 = feat[3 * s + 2];
        #pragma unroll
        for (int k = 0; k < 16; ++k) {
            float a = fmaf(ed.y, w1r[0][k], fmaf(ed.z, w1r[1][k], ed.w * w1r[2][k]));
            float h = a > 0.0f ? a : 0.0f;
            O[k][0] = fmaf(h, f0, O[k][0]);
            O[k][1] = fmaf(h, f1, O[k][1]);
            O[k][2] = fmaf(h, f2, O[k][2]);
        }
    }

    float p0 = 0.f, p1 = 0.f, p2 = 0.f, p3 = 0.f;
    #pragma unroll
    for (int k = 0; k < 16; ++k)
        #pragma unroll
        for (int u = 0; u < 3; ++u) {
            const float4 q = *(const float4*)&lw[k * 20 + u * 4];
            float o = O[k][u];
            p0 = fmaf(o, q.x, p0); p1 = fmaf(o, q.y, p1);
            p2 = fmaf(o, q.z, p2); p3 = fmaf(o, q.w, p3);
        }
    p0 += __shfl_xor(p0, 1); p1 += __shfl_xor(p1, 1);
    p2 += __shfl_xor(p2, 1); p3 += __shfl_xor(p3, 1);
    p0 += __shfl_xor(p0, 2); p1 += __shfl_xor(p1, 2);
    p2 += __shfl_xor(p2, 2); p3 += __shfl_xor(p3, 2);
    if (t == 0) {
        const float S = 0.051031036307982884f; // sqrt2/sqrt3/16
        float4 o; o.x = p0 * S; o.y = p1 * S; o.z = p2 * S; o.w = p3 * S;
        ((float4*)xout)[nd] = o;
    }
}

__global__ __launch_bounds__(256) void k_node_core(
    const float4* __restrict__ xin, const float4* __restrict__ edata,
    const int2* __restrict__ offs2,
    const float* __restrict__ w1, const float* __restrict__ w2,
    float* __restrict__ xout, int n)
{
    __shared__ float lw[16 * 20];
    {
        int idx = threadIdx.x;
        int k = idx >> 4, r = idx & 15;
        lw[k * 20 + r] = w2[k * 48 + r];
    }
    __syncthreads();

    int g = blockIdx.x * 256 + threadIdx.x;
    int nd = g >> 2;
    if (nd >= n) return;
    int t = g & 3;

    float w1r[3][16];   // wave-uniform -> SGPRs
    #pragma unroll
    for (int j = 0; j < 3; ++j)
        #pragma unroll
        for (int k = 0; k < 16; ++k) w1r[j][k] = uload(&w1[j * 16 + k]);

    float O[16][4];
    #pragma unroll
    for (int k = 0; k < 16; ++k)
        #pragma unroll
        for (int u = 0; u < 4; ++u) O[k][u] = 0.0f;

    int2 se = offs2[nd];
    for (int e = se.x + t; e < se.y; e += 4) {
        float4 ed = edata[e];
        int s = __float_as_int(ed.x);
        float4 x = xin[s];
        #pragma unroll
        for (int k = 0; k < 16; ++k) {
            float a = fmaf(ed.y, w1r[0][k], fmaf(ed.z, w1r[1][k], ed.w * w1r[2][k]));
            float h = a > 0.0f ? a : 0.0f;
            O[k][0] = fmaf(h, x.x, O[k][0]);
            O[k][1] = fmaf(h, x.y, O[k][1]);
            O[k][2] = fmaf(h, x.z, O[k][2]);
            O[k][3] = fmaf(h, x.w, O[k][3]);
        }
    }

    float p0 = 0.f, p1 = 0.f, p2 = 0.f, p3 = 0.f;
    #pragma unroll
    for (int k = 0; k < 16; ++k)
        #pragma unroll
        for (int u = 0; u < 4; ++u) {
            const float4 q = *(const float4*)&lw[k * 20 + u * 4];
            float o = O[k][u];
            p0 = fmaf(o, q.x, p0); p1 = fmaf(o, q.y, p1);
            p2 = fmaf(o, q.z, p2); p3 = fmaf(o, q.w, p3);
        }
    p0 += __shfl_xor(p0, 1); p1 += __shfl_xor(p1, 1);
    p2 += __shfl_xor(p2, 1); p3 += __shfl_xor(p3, 1);
    p0 += __shfl_xor(p0, 2); p1 += __shfl_xor(p1, 2);
    p2 += __shfl_xor(p2, 2); p3 += __shfl_xor(p3, 2);
    if (t == 0) {
        const float S = 0.04419417382415922f; // sqrt2*0.5/16
        float4 o; o.x = p0 * S; o.y = p1 * S; o.z = p2 * S; o.w = p3 * S;
        ((float4*)xout)[nd] = o;
    }
}

// fc3 + folded 1x1 conv via precomputed G[16][4][2].
__global__ __launch_bounds__(256) void k_node_fc3_final(
    const float4* __restrict__ xin, const float4* __restrict__ edata,
    const int2* __restrict__ offs2,
    const float* __restrict__ w1, const float* __restrict__ gbuf,
    const float* __restrict__ cb,
    float* __restrict__ out, int n)
{
    __shared__ float lg[128];
    if (threadIdx.x < 128) lg[threadIdx.x] = gbuf[threadIdx.x];
    __syncthreads();

    int g = blockIdx.x * 256 + threadIdx.x;
    int nd = g >> 2;
    if (nd >= n) return;
    int t = g & 3;

    float w1r[3][16];   // wave-uniform -> SGPRs
    #pragma unroll
    for (int j = 0; j < 3; ++j)
        #pragma unroll
        for (int k = 0; k < 16; ++k) w1r[j][k] = uload(&w1[j * 16 + k]);

    float O[16][4];
    #pragma unroll
    for (int k = 0; k < 16; ++k)
        #pragma unroll
        for (int u = 0; u < 4; ++u) O[k][u] = 0.0f;

    int2 se = offs2[nd];
    for (int e = se.x + t; e < se.y; e += 4) {
        float4 ed = edata[e];
        int s = __float_as_int(ed.x);
        float4 x = xin[s];
        #pragma unroll
        for (int k = 0; k < 16; ++k) {
            float a = fmaf(ed.y, w1r[0][k], fmaf(ed.z, w1r[1][k], ed.w * w1r[2][k]));
            float h = a > 0.0f ? a : 0.0f;
            O[k][0] = fmaf(h, x.x, O[k][0]);
            O[k][1] = fmaf(h, x.y, O[k][1]);
            O[k][2] = fmaf(h, x.z, O[k][2]);
            O[k][3] = fmaf(h, x.w, O[k][3]);
        }
    }

    float a0 = 0.f, a1 = 0.f;
    #pragma unroll
    for (int k = 0; k < 16; ++k)
        #pragma unroll
        for (int u = 0; u < 4; ++u) {
            float o = O[k][u];
            const float2 q = *(const float2*)&lg[(k * 4 + u) * 2];
            a0 = fmaf(o, q.x, a0);
            a1 = fmaf(o, q.y, a1);
        }
    a0 += __shfl_xor(a0, 1); a1 += __shfl_xor(a1, 1);
    a0 += __shfl_xor(a0, 2); a1 += __shfl_xor(a1, 2);
    if (t == 0) {
        const float S = 0.04419417382415922f;
        float2 o; o.x = fmaf(a0, S, cb[0]); o.y = fmaf(a1, S, cb[1]);
        ((float2*)out)[nd] = o;
    }
}

// ---------------------------------------------------------------------------

extern "C" void kernel_launch(void* const* d_in, const int* in_sizes, int n_in,
                              void* d_out, int out_size, void* d_ws, size_t ws_size,
                              hipStream_t stream) {
    const float* pos     = (const float*)d_in[0];
    const float* feat    = (const float*)d_in[1];
    const int*   esrc    = (const int*)d_in[2];
    const int*   edst    = (const int*)d_in[3];
    const float* fc1_w1  = (const float*)d_in[4];
    const float* fc1_w2  = (const float*)d_in[5];
    const float* core_w1 = (const float*)d_in[6];
    const float* core_w2 = (const float*)d_in[7];
    const float* fc3_w1  = (const float*)d_in[8];
    const float* fc3_w2  = (const float*)d_in[9];
    const float* conv_w  = (const float*)d_in[10];
    const float* conv_b  = (const float*)d_in[11];
    float* out = (float*)d_out;

    const int E = in_sizes[2];          // 1600000
    const int N = in_sizes[0] / 3;      // 100000
    const int nb = (N + 255) >> 8;      // 391

    float4* ebuf = (float4*)d_ws;                        // nb*BCAP float4
    int* ptmp  = (int*)(ebuf + (size_t)nb * BCAP);       // nb*BCAP int
    float* xa  = (float*)(ptmp + (size_t)nb * BCAP);     // 4N
    float* xb  = xa + (size_t)4 * N;                     // 4N
    int2* offs2 = (int2*)(xb + (size_t)4 * N);           // N
    int* gcur  = (int*)(offs2 + N);                      // nb
    float* gbuf = (float*)(gcur + ((nb + 3) & ~3));      // 128

    int g4 = (4 * N + 255) / 256;

    hipMemsetAsync(gcur, 0, (size_t)nb * sizeof(int), stream);
    k_bin<<<(E + 8191) / 8192, 1024, 0, stream>>>(esrc, edst, gcur, ptmp,
                                                  fc3_w2, conv_w, gbuf, E, nb);
    k_build<<<nb, 1024, 0, stream>>>(gcur, ptmp, pos, ebuf, offs2, N, nb);

    k_node_l1<<<g4, 256, 0, stream>>>(feat, ebuf, offs2, fc1_w1, fc1_w2, xa, N);
    k_node_core<<<g4, 256, 0, stream>>>((const float4*)xa, ebuf, offs2,
                                        core_w1 + 0, core_w2 + 0, xb, N);
    k_node_core<<<g4, 256, 0, stream>>>((const float4*)xb, ebuf, offs2,
                                        core_w1 + 48, core_w2 + 768, xa, N);
    k_node_core<<<g4, 256, 0, stream>>>((const float4*)xa, ebuf, offs2,
                                        core_w1 + 96, core_w2 + 1536, xb, N);
    k_node_fc3_final<<<g4, 256, 0, stream>>>((const float4*)xb, ebuf, offs2,
                                             fc3_w1, gbuf, conv_b, out, N);
}